// Round 2
// baseline (1032.253 us; speedup 1.0000x reference)
//
#include <hip/hip_runtime.h>

// Problem constants (from reference setup_inputs)
constexpr int B_ = 32, C_ = 64, H_ = 64, W_ = 256, O_ = 64, E_ = 4, R_ = 4;
constexpr int KK = 3;                 // kernel size
constexpr int CKK = C_ * KK * KK;     // 576
constexpr float ALPHA_ = 1.0f;

// ---------------------------------------------------------------------------
// Kernel 1: merge LoRA into conv weights per expert (conv is linear in W).
// W_eff[e][o][c][kh][kw] = W_conv[o][c][kh][kw]
//                        + (ALPHA/R) * sum_r W_B[e][o][r] * W_A[e][r][c][kh][kw]
// Total elements: 4*64*576 = 147456 (tiny; 576 KB fp32 in d_ws).
// ---------------------------------------------------------------------------
__global__ __launch_bounds__(256) void merge_weights_k(
    const float* __restrict__ Wc,
    const float* __restrict__ Wa,
    const float* __restrict__ Wb,
    float* __restrict__ Weff)
{
    int idx = blockIdx.x * 256 + threadIdx.x;
    constexpr int total = E_ * O_ * CKK;
    if (idx >= total) return;
    int ckk = idx % CKK;
    int o   = (idx / CKK) % O_;
    int e   = idx / (O_ * CKK);
    float acc = Wc[o * CKK + ckk];
#pragma unroll
    for (int r = 0; r < R_; ++r) {
        float wb = Wb[(e * O_ + o) * R_ + r];
        float wa = Wa[(e * R_ + r) * CKK + ckk];
        acc += (ALPHA_ / R_) * wb * wa;
    }
    Weff[idx] = acc;
}

// ---------------------------------------------------------------------------
// Kernel 2: direct 3x3 SAME conv, per-batch expert weight.
// Grid: (W/WT, H, B), 256 threads. LDS-staged input tile (3 rows x C x WT+2).
// Each thread: 4 consecutive o  x  4 consecutive w register tile, fp32 acc.
// ---------------------------------------------------------------------------
constexpr int WT = 64;          // output width per block
constexpr int XS_STRIDE = 72;   // padded row stride (floats): breaks 64/66 patterns

__global__ __launch_bounds__(256) void conv_k(
    const float* __restrict__ x,
    const int* __restrict__ sid,
    const float* __restrict__ Weff,
    float* __restrict__ out)
{
    __shared__ float xs[3 * C_ * XS_STRIDE];   // 55.3 KB

    const int wt  = blockIdx.x;   // 0..3
    const int h   = blockIdx.y;   // 0..63
    const int b   = blockIdx.z;   // 0..31
    const int tid = threadIdx.x;
    const int e   = __builtin_amdgcn_readfirstlane(sid[b]);

    const int w0 = wt * WT;

    // Stage input: rows h-1..h+1, all 64 channels, cols w0-1 .. w0+WT (66 wide), zero-pad OOB.
    for (int i = tid; i < 3 * C_ * (WT + 2); i += 256) {
        int ww = i % (WT + 2);
        int c  = (i / (WT + 2)) % C_;
        int kh = i / ((WT + 2) * C_);
        int hh = h + kh - 1;
        int gw = w0 + ww - 1;
        float v = 0.0f;
        if ((unsigned)hh < (unsigned)H_ && (unsigned)gw < (unsigned)W_)
            v = x[(((size_t)b * C_ + c) * H_ + hh) * W_ + gw];
        xs[(kh * C_ + c) * XS_STRIDE + ww] = v;
    }
    __syncthreads();

    const int wl = (tid & 15) * 4;   // this thread's first w within the tile
    const int ob = (tid >> 4) * 4;   // this thread's first o

    float acc[4][4];
#pragma unroll
    for (int oi = 0; oi < 4; ++oi)
#pragma unroll
        for (int j = 0; j < 4; ++j) acc[oi][j] = 0.0f;

    const float* __restrict__ wp = Weff + (size_t)e * O_ * CKK;

    for (int c = 0; c < C_; ++c) {
        // 6 input values per kh row cover the 4 outputs' 3-tap windows
        float xv[3][6];
#pragma unroll
        for (int kh = 0; kh < 3; ++kh) {
            const float* row = &xs[(kh * C_ + c) * XS_STRIDE + wl];
#pragma unroll
            for (int j = 0; j < 6; ++j) xv[kh][j] = row[j];
        }
#pragma unroll
        for (int oi = 0; oi < 4; ++oi) {
            const float* wr = wp + ((ob + oi) * C_ + c) * 9;
            float w9[9];
#pragma unroll
            for (int t = 0; t < 9; ++t) w9[t] = wr[t];
#pragma unroll
            for (int kh = 0; kh < 3; ++kh) {
#pragma unroll
                for (int j = 0; j < 4; ++j) {
                    acc[oi][j] += w9[kh * 3 + 0] * xv[kh][j + 0]
                                + w9[kh * 3 + 1] * xv[kh][j + 1]
                                + w9[kh * 3 + 2] * xv[kh][j + 2];
                }
            }
        }
    }

    // Store: float4 per o-row; (w0+wl) % 4 == 0 -> 16B aligned.
#pragma unroll
    for (int oi = 0; oi < 4; ++oi) {
        int o = ob + oi;
        size_t base = (((size_t)b * O_ + o) * H_ + h) * W_ + w0 + wl;
        float4 v4 = make_float4(acc[oi][0], acc[oi][1], acc[oi][2], acc[oi][3]);
        *reinterpret_cast<float4*>(&out[base]) = v4;
    }
}

// ---------------------------------------------------------------------------
extern "C" void kernel_launch(void* const* d_in, const int* in_sizes, int n_in,
                              void* d_out, int out_size, void* d_ws, size_t ws_size,
                              hipStream_t stream)
{
    const float* x   = (const float*)d_in[0];
    const int*   sid = (const int*)d_in[1];
    const float* Wc  = (const float*)d_in[2];
    const float* Wa  = (const float*)d_in[3];
    const float* Wb  = (const float*)d_in[4];
    float*       out = (float*)d_out;

    float* Weff = (float*)d_ws;   // E*O*C*9 fp32 = 576 KB, fully rewritten each call

    constexpr int total_w = E_ * O_ * CKK;
    merge_weights_k<<<(total_w + 255) / 256, 256, 0, stream>>>(Wc, Wa, Wb, Weff);

    dim3 grid(W_ / WT, H_, B_);
    conv_k<<<grid, 256, 0, stream>>>(x, sid, Weff, out);
}

// Round 3
// 631.501 us; speedup vs baseline: 1.6346x; 1.6346x over previous
//
#include <hip/hip_runtime.h>
#include <hip/hip_bf16.h>

typedef __attribute__((ext_vector_type(8))) short bf16x8;   // 8 bf16 = 4 VGPRs
typedef __attribute__((ext_vector_type(4))) float f32x4;    // MFMA 16x16 accumulator

constexpr int B_ = 32, C_ = 64, H_ = 64, W_ = 256, O_ = 64, E_ = 4, R_ = 4;
constexpr float SCALE = 1.0f / R_;   // ALPHA / r

// Spatial tile per block: 8 h-rows x 32 w. Staged input: 10 x 36 (halo), 64 c.
constexpr int TH = 8, TW = 32;
constexpr int SH = TH + 2, SW = TW + 4;
constexpr int CS = 72;   // LDS c-stride (bf16): 144 B = 9 x 16 B (odd multiple -> conflict-free b128)

// ---------------------------------------------------------------------------
// Merge LoRA into conv weights, written DIRECTLY in MFMA A-fragment order:
// Wfrag[e][ob][f][lane][j], f = tap*2 + kb,
//   value = Weff[e][ o = ob*16 + (lane&15) ][ c = kb*32 + (lane>>4)*8 + j ][tap]
// where Weff = W_conv + SCALE * sum_r W_B[e][o][r] * W_A[e][r][c][tap].
// Total 4*4*18*64*8 = 147456 bf16 (288 KB in d_ws).
// ---------------------------------------------------------------------------
__global__ __launch_bounds__(256) void merge_k(
    const float* __restrict__ Wc, const float* __restrict__ Wa,
    const float* __restrict__ Wb, __hip_bfloat16* __restrict__ Wfrag)
{
    int t = blockIdx.x * 256 + threadIdx.x;       // 0 .. 147455 (grid exact)
    int j    = t & 7;
    int lane = (t >> 3) & 63;
    int f    = (t >> 9) % 18;
    int ob   = (t / (512 * 18)) & 3;
    int e    = t / (512 * 18 * 4);
    int q = lane >> 4, n = lane & 15;
    int o = ob * 16 + n;
    int kb = f & 1, tap = f >> 1;
    int c = kb * 32 + q * 8 + j;
    float acc = Wc[(o * C_ + c) * 9 + tap];
#pragma unroll
    for (int r = 0; r < R_; ++r)
        acc += SCALE * Wb[(e * O_ + o) * R_ + r] * Wa[((e * R_ + r) * C_ + c) * 9 + tap];
    Wfrag[t] = __float2bfloat16(acc);
}

// ---------------------------------------------------------------------------
// Implicit-GEMM conv: out[b][o][h][w] = sum_{c,dh,dw} x[b][c][h+dh-1][w+dw-1] * Weff[e_b][o][c][dh][dw]
// Block: 64 o x (8h x 32w) of one image. 4 waves, each owns 16 o; weights in VGPRs.
// K-loop: 18 steps (9 taps x 2 c-blocks) of mfma_f32_16x16x32_bf16.
// ---------------------------------------------------------------------------
__global__ __launch_bounds__(256, 2) void conv_mfma_k(
    const float* __restrict__ x, const int* __restrict__ sid,
    const __hip_bfloat16* __restrict__ Wfrag, float* __restrict__ out)
{
    __shared__ __hip_bfloat16 xs[SH * SW * CS];   // 51840 B

    const int tid = threadIdx.x;
    const int w0 = blockIdx.x * TW, h0 = blockIdx.y * TH, b = blockIdx.z;
    const int e = sid[b];

    const int lane = tid & 63, wave = tid >> 6;
    const int q = lane >> 4, n = lane & 15;

    // Weight fragments for this wave's 16-o block: 18 x global_load_dwordx4 (L2-resident),
    // issued before staging sync so they overlap the LDS fill.
    bf16x8 wf[18];
    const bf16x8* wg = reinterpret_cast<const bf16x8*>(Wfrag) + (size_t)(e * 4 + wave) * 18 * 64;
#pragma unroll
    for (int f = 0; f < 18; ++f) wf[f] = wg[f * 64 + lane];

    // Stage x tile -> LDS bf16, layout [hh][ww][c]. Lanes walk ww => coalesced global reads.
    for (int i = tid; i < SH * SW * C_; i += 256) {
        int ww = i % SW;
        int c  = (i / SW) % C_;
        int hh = i / (SW * C_);
        int gh = h0 + hh - 1, gw = w0 + ww - 1;
        float v = 0.0f;
        if ((unsigned)gh < (unsigned)H_ && (unsigned)gw < (unsigned)W_)
            v = x[((size_t)(b * C_ + c) * H_ + gh) * W_ + gw];
        xs[(hh * SW + ww) * CS + c] = __float2bfloat16(v);
    }
    __syncthreads();

    f32x4 acc[TH][2];
#pragma unroll
    for (int hr = 0; hr < TH; ++hr)
#pragma unroll
        for (int wb = 0; wb < 2; ++wb)
            acc[hr][wb] = f32x4{0.f, 0.f, 0.f, 0.f};

#pragma unroll
    for (int f = 0; f < 18; ++f) {
        const int tap = f >> 1, kb = f & 1;
        const int dh = tap / 3, dw = tap % 3;
        const int base = (dh * SW + n + dw) * CS + kb * 32 + q * 8;  // + hr*SW*CS + wb*16*CS
#pragma unroll
        for (int hr = 0; hr < TH; ++hr) {
#pragma unroll
            for (int wb = 0; wb < 2; ++wb) {
                int off = base + (hr * SW + wb * 16) * CS;
                bf16x8 bf = *reinterpret_cast<const bf16x8*>(&xs[off]);
                acc[hr][wb] = __builtin_amdgcn_mfma_f32_16x16x32_bf16(wf[f], bf, acc[hr][wb], 0, 0, 0);
            }
        }
    }

    // C/D layout: col(=w) = lane&15, row(=o within 16) = (lane>>4)*4 + reg.
#pragma unroll
    for (int hr = 0; hr < TH; ++hr)
#pragma unroll
        for (int wb = 0; wb < 2; ++wb)
#pragma unroll
            for (int r = 0; r < 4; ++r) {
                int o = wave * 16 + q * 4 + r;
                out[((size_t)(b * O_ + o) * H_ + h0 + hr) * W_ + w0 + wb * 16 + n] = acc[hr][wb][r];
            }
}

// ---------------------------------------------------------------------------
extern "C" void kernel_launch(void* const* d_in, const int* in_sizes, int n_in,
                              void* d_out, int out_size, void* d_ws, size_t ws_size,
                              hipStream_t stream)
{
    const float* x   = (const float*)d_in[0];
    const int*   sid = (const int*)d_in[1];
    const float* Wc  = (const float*)d_in[2];
    const float* Wa  = (const float*)d_in[3];
    const float* Wb  = (const float*)d_in[4];
    float*       out = (float*)d_out;

    __hip_bfloat16* Wfrag = (__hip_bfloat16*)d_ws;   // 294912 B, fully rewritten each call

    merge_k<<<E_ * O_ * C_ * 9 / 256, 256, 0, stream>>>(Wc, Wa, Wb, Wfrag);

    dim3 grid(W_ / TW, H_ / TH, B_);
    conv_mfma_k<<<grid, 256, 0, stream>>>(x, sid, Wfrag, out);
}

// Round 4
// 481.598 us; speedup vs baseline: 2.1434x; 1.3113x over previous
//
#include <hip/hip_runtime.h>
#include <hip/hip_bf16.h>

typedef __attribute__((ext_vector_type(8)))  short bf16x8;   // 8 bf16 = 4 VGPRs
typedef __attribute__((ext_vector_type(16))) float f32x16;   // 32x32 MFMA accumulator

constexpr int Bn = 32, Cn = 64, Hn = 64, Wn = 256, On = 64, En = 4, Rn = 4;
constexpr float SCALE = 1.0f / Rn;

constexpr int WTILE  = 128;         // w per block
constexpr int HSTRIP = 8;           // output rows per block
constexpr int SLOT_B = 130 * 128;   // bytes per x-row ring slot (130 ww x 64 c x 2B)
constexpr int EPI_OS = 12;          // epilogue o-stride in floats (8 + pad, 16B-mult)

// ---------------------------------------------------------------------------
// Merge LoRA into conv weights, in 32x32x16 A-fragment order:
// Wfrag[e][mh][s][lane][j]:  o = mh*32 + (lane&31),
//   k: tap = s>>2, c = (s&3)*16 + (lane>>5)*8 + j
// value = Wc[o][c][tap] + SCALE * sum_r Wb[e][o][r]*Wa[e][r][c][tap]
// ---------------------------------------------------------------------------
__global__ __launch_bounds__(256) void merge_k(
    const float* __restrict__ Wc, const float* __restrict__ Wa,
    const float* __restrict__ Wb, __hip_bfloat16* __restrict__ Wfrag)
{
    int t = blockIdx.x * 256 + threadIdx.x;          // 0..147455 exact
    int j    = t & 7;
    int lane = (t >> 3) & 63;
    int g    = t >> 9;                               // (e*2+mh)*36 + s
    int s    = g % 36;
    int mh   = (g / 36) & 1;
    int e    = g / 72;
    int m = lane & 31, half = lane >> 5;
    int o = mh * 32 + m;
    int tap = s >> 2, cq = s & 3;
    int c = cq * 16 + half * 8 + j;
    float acc = Wc[(o * Cn + c) * 9 + tap];
#pragma unroll
    for (int r = 0; r < Rn; ++r)
        acc += SCALE * Wb[(e * On + o) * Rn + r] * Wa[((e * Rn + r) * Cn + c) * 9 + tap];
    Wfrag[t] = __float2bfloat16(acc);
}

// ---------------------------------------------------------------------------
// Ring-pipelined implicit-GEMM conv. Block = (b, w-half, 8-row h-strip).
// 4 waves: (mh = wave&1) -> 32 o, (nh = wave>>1) -> 64 w. Weights in VGPRs.
// ---------------------------------------------------------------------------
__global__ __launch_bounds__(256, 2) void conv_k(
    const float* __restrict__ x, const int* __restrict__ sid,
    const __hip_bfloat16* __restrict__ Wfrag, float* __restrict__ out)
{
    __shared__ __align__(16) char  xs[4 * SLOT_B];        // 66560 B ring
    __shared__ __align__(16) float ep[4 * 64 * EPI_OS];   // 12288 B epilogue

    const int tid = threadIdx.x;
    const int w0  = blockIdx.x * WTILE;
    const int h0  = blockIdx.y * HSTRIP;
    const int b   = blockIdx.z;
    const int e   = sid[b];

    const int lane = tid & 63, wave = tid >> 6;
    const int mh = wave & 1, nh = wave >> 1;
    const int n = lane & 31, half = lane >> 5;

    // A fragments: 36 x bf16x8, loaded once (L2-resident), live in VGPRs.
    bf16x8 wf[36];
    const bf16x8* wg = reinterpret_cast<const bf16x8*>(Wfrag) + (size_t)(e * 2 + mh) * 36 * 64;
#pragma unroll
    for (int s = 0; s < 36; ++s) wf[s] = wg[s * 64 + lane];

    float* epw = ep + wave * 64 * EPI_OS;

    // --- staging helpers: row rx (x-row = h0+rx) -> ring slot (rx+1)&3 ---
    float stg[5][8];
    auto stage_load = [&](int rx) {
        const int gh = h0 + rx;
        const bool ghv = (unsigned)gh < (unsigned)Hn;
#pragma unroll
        for (int r = 0; r < 5; ++r) {
            int t = r * 256 + tid;
            int cb = t >> 7, ww = t & 127;
            if (r == 4) { cb = (t - 1024) >> 1; ww = 128 + (t & 1); }
            bool active = (r < 4) || (tid < 16);
            int gw = w0 + ww - 1;
            bool v = active && ghv && ((unsigned)gw < (unsigned)Wn);
#pragma unroll
            for (int i = 0; i < 8; ++i)
                stg[r][i] = v ? x[(((size_t)b * Cn + cb * 8 + i) * Hn + gh) * Wn + gw] : 0.0f;
        }
    };
    auto stage_store = [&](int rx) {
        const int slot = (rx + 1) & 3;
#pragma unroll
        for (int r = 0; r < 5; ++r) {
            int t = r * 256 + tid;
            int cb = t >> 7, ww = t & 127;
            if (r == 4) { cb = (t - 1024) >> 1; ww = 128 + (t & 1); }
            bool active = (r < 4) || (tid < 16);
            if (!active) continue;
            union { __hip_bfloat16 u[8]; bf16x8 v8; } pk;
#pragma unroll
            for (int i = 0; i < 8; ++i) pk.u[i] = __float2bfloat16(stg[r][i]);
            int off = slot * SLOT_B + ww * 128 + ((cb ^ (ww & 7)) * 16);
            *reinterpret_cast<bf16x8*>(xs + off) = pk.v8;
        }
    };

    // prologue: x rows h0-1, h0, h0+1
    stage_load(-1); stage_store(-1);
    stage_load(0);  stage_store(0);
    stage_load(1);  stage_store(1);
    __syncthreads();

    for (int st = 0; st < HSTRIP; ++st) {
        // 1. issue next row's global loads (hidden under compute)
        const bool do_stage = (st + 2 <= HSTRIP);
        if (do_stage) stage_load(st + 2);

        // 2. compute output row h0+st
        f32x16 a[2];
#pragma unroll
        for (int nf = 0; nf < 2; ++nf)
#pragma unroll
            for (int i = 0; i < 16; ++i) a[nf][i] = 0.0f;

#pragma unroll
        for (int s = 0; s < 36; ++s) {
            const int tap = s >> 2, cq = s & 3;
            const int dh = tap / 3, dw = tap % 3;
            const int slotbase = ((st + dh) & 3) * SLOT_B;
#pragma unroll
            for (int nf = 0; nf < 2; ++nf) {
                int ww = nh * 64 + nf * 32 + n + dw;                 // 0..129
                int off = slotbase + ww * 128 + (((cq * 2 + half) ^ (ww & 7)) * 16);
                bf16x8 bf = *reinterpret_cast<const bf16x8*>(xs + off);
                a[nf] = __builtin_amdgcn_mfma_f32_32x32x16_bf16(wf[s], bf, a[nf], 0, 0, 0);
            }
        }

        // 3. write staged row to its ring slot
        if (do_stage) stage_store(st + 2);

        // 4. epilogue: per-wave LDS transpose -> 256B-contiguous stores
        const int hrow = h0 + st;
#pragma unroll
        for (int t4 = 0; t4 < 4; ++t4) {
            // write regs 4*t4..4*t4+3 (o-contig quad) per nf: layout [w 64][o 8+pad]
#pragma unroll
            for (int nf = 0; nf < 2; ++nf) {
                float4 v = make_float4(a[nf][4 * t4 + 0], a[nf][4 * t4 + 1],
                                       a[nf][4 * t4 + 2], a[nf][4 * t4 + 3]);
                *reinterpret_cast<float4*>(&epw[(nf * 32 + n) * EPI_OS + half * 4]) = v;
            }
            // read back w-contig per o; same-wave LDS ops are in-order
#pragma unroll
            for (int k = 0; k < 4; ++k) {
                int mrel = 2 * k + half;           // 0..7
                int wbuf = 2 * n;                  // 0..62
                float lo = epw[wbuf * EPI_OS + mrel];
                float hi = epw[(wbuf + 1) * EPI_OS + mrel];
                int o = mh * 32 + 8 * t4 + mrel;
                size_t oidx = (((size_t)b * On + o) * Hn + hrow) * Wn + w0 + nh * 64 + wbuf;
                float2 v2; v2.x = lo; v2.y = hi;
                *reinterpret_cast<float2*>(&out[oidx]) = v2;
            }
        }

        // 5. publish staged row / protect ring reuse
        __syncthreads();
    }
}

// ---------------------------------------------------------------------------
extern "C" void kernel_launch(void* const* d_in, const int* in_sizes, int n_in,
                              void* d_out, int out_size, void* d_ws, size_t ws_size,
                              hipStream_t stream)
{
    const float* x   = (const float*)d_in[0];
    const int*   sid = (const int*)d_in[1];
    const float* Wc  = (const float*)d_in[2];
    const float* Wa  = (const float*)d_in[3];
    const float* Wb  = (const float*)d_in[4];
    float*       out = (float*)d_out;

    __hip_bfloat16* Wfrag = (__hip_bfloat16*)d_ws;   // 294912 B, rewritten each call

    merge_k<<<En * 2 * 36 * 64 * 8 / 256, 256, 0, stream>>>(Wc, Wa, Wb, Wfrag);

    dim3 grid(Wn / WTILE, Hn / HSTRIP, Bn);
    conv_k<<<grid, 256, 0, stream>>>(x, sid, Wfrag, out);
}